// Round 9
// baseline (20506.857 us; speedup 1.0000x reference)
//
#include <hip/hip_runtime.h>

#define HIDDEN   2048
#define T_STEPS  8192
#define WASHOUT  200
#define NWG      64
#define NTHR     512
#define NWAVE    (NTHR / 64)                 // 8 waves
#define ROWS_PER_WG   (HIDDEN / NWG)         // 32
#define ROWS_PER_WAVE (ROWS_PER_WG / NWAVE)  // 4
#define NSUB     4                           // 4 subgroups of 512 state vals
#define NREPL    8                           // one mailbox replica per XCD
#define REPL     (2 * HIDDEN)                // ull elements per replica (32 KB)

// ws layout: NREPL replicas of {unsigned long long pairs[2][HIDDEN]}.
// Pair = {value:hi32, step:lo32}: one 8B unit carries payload+tag.
// 0xAA poison tags self-correct across graph replays.
//
// R22 (this round): BARRIER-1 REMOVAL + direct poll-consume.
// R8 post-mortem: NTHR=1024 regressed (+3%); VGPR_Count=48 < 64 pinned
// weights means launch_bounds(1024,1)'s 128-reg cap pushed weights to the
// AGPR side of the unified file (no FETCH balloon = no scratch) -> an
// accvgpr_read per FMA, the R0 disease. Reverted to 512 thr / 8 waves.
// This round: the 2-buffer tag protocol makes barrier 1 + x_s staging
// REMOVABLE -- slot p=t&1 can only be overwritten with t+2 after every WG
// published t+1, which transitively requires every wave consumed tag t.
// So each wave polls ALL 2048 state values itself (4 subgroups x 4
// dwordx4/lane, L2-local replica lines shared by the XCD's waves), spins
// per subgroup, and FMAs each subgroup AS IT ARRIVES: deletes barrier 1 +
// the LDS staging round trip, and overlaps early-group FMAs with the wait
// for straggler producers (expected exposed tail 128 -> ~64 FMAs).
// Barrier 2 stays (consolidated publish needs all 32 rows; readout slack
// argument unchanged from R7: no wave can rewrite fresh[] sooner than a
// fabric round trip after barrier 2, readout is ~50 cy).
// Kept (each isolated): per-XCD replicas (R5), sc1 cacheable polls / NO nt
// (R2), per-wave full-line publish + permlane swaps + fast tanh (R7),
// 128 VGPR-pinned weights with compile-time indices (R1/R3),
// launch_bounds(512,1) (R3/R8 reg-cap lessons).

// DPP add: x + dpp_perm(x). All-VALU (no DS round trip).
#define DPP_ADD(x, ctrl) ((x) + __int_as_float(__builtin_amdgcn_update_dpp( \
    0, __float_as_int(x), ctrl, 0xF, 0xF, true)))

typedef unsigned uint4v __attribute__((ext_vector_type(4)));
typedef unsigned uint2v __attribute__((ext_vector_type(2)));

// 64-lane sum via permlane{16,32}_swap self-swap (both outputs summed ->
// direction-agnostic). Builtin form only: R19's asm form let the allocator
// coalesce the two same-value "+v" operands into one register.
#define PERMLANE_SUM_1632(h)                                         \
  {                                                                  \
    uint2v s16 = __builtin_amdgcn_permlane16_swap(                   \
        __float_as_uint(h), __float_as_uint(h), false, false);       \
    h = __uint_as_float(s16.x) + __uint_as_float(s16.y);             \
    uint2v s32 = __builtin_amdgcn_permlane32_swap(                   \
        __float_as_uint(h), __float_as_uint(h), false, false);       \
    h = __uint_as_float(s32.x) + __uint_as_float(s32.y);             \
  }

// Poll subgroup s (512 state values: pairs [s*512, s*512+512)) until its
// tags read `want`, then FMA its 8 values/lane into d0..d3. s is a
// compile-time literal -> all wreg indices are constant (no spill).
#define POLLSUB(s)                                                        \
  {                                                                       \
    const unsigned long long* bp = base + (s) * 512;                      \
    uint4v A0, A1, A2, A3;  /* [tag0,val0,tag1,val1] x4 */                \
    for (;;) {                                                            \
      asm volatile(                                                       \
          "global_load_dwordx4 %0, %4, off sc1\n\t"                       \
          "global_load_dwordx4 %1, %4, off offset:1024 sc1\n\t"           \
          "global_load_dwordx4 %2, %4, off offset:2048 sc1\n\t"           \
          "global_load_dwordx4 %3, %4, off offset:3072 sc1\n\t"           \
          "s_waitcnt vmcnt(0)"                                            \
          : "=&v"(A0), "=&v"(A1), "=&v"(A2), "=&v"(A3)                    \
          : "v"(bp) : "memory");                                          \
      if (((A0.x == want) & (A0.z == want) &                              \
           (A1.x == want) & (A1.z == want)) &                             \
          ((A2.x == want) & (A2.z == want) &                              \
           (A3.x == want) & (A3.z == want))) break;                       \
    }                                                                     \
    d0 = fmaf(wreg[0][8*(s)+0], __uint_as_float(A0.y), d0);               \
    d0 = fmaf(wreg[0][8*(s)+1], __uint_as_float(A0.w), d0);               \
    d0 = fmaf(wreg[0][8*(s)+2], __uint_as_float(A1.y), d0);               \
    d0 = fmaf(wreg[0][8*(s)+3], __uint_as_float(A1.w), d0);               \
    d0 = fmaf(wreg[0][8*(s)+4], __uint_as_float(A2.y), d0);               \
    d0 = fmaf(wreg[0][8*(s)+5], __uint_as_float(A2.w), d0);               \
    d0 = fmaf(wreg[0][8*(s)+6], __uint_as_float(A3.y), d0);               \
    d0 = fmaf(wreg[0][8*(s)+7], __uint_as_float(A3.w), d0);               \
    d1 = fmaf(wreg[1][8*(s)+0], __uint_as_float(A0.y), d1);               \
    d1 = fmaf(wreg[1][8*(s)+1], __uint_as_float(A0.w), d1);               \
    d1 = fmaf(wreg[1][8*(s)+2], __uint_as_float(A1.y), d1);               \
    d1 = fmaf(wreg[1][8*(s)+3], __uint_as_float(A1.w), d1);               \
    d1 = fmaf(wreg[1][8*(s)+4], __uint_as_float(A2.y), d1);               \
    d1 = fmaf(wreg[1][8*(s)+5], __uint_as_float(A2.w), d1);               \
    d1 = fmaf(wreg[1][8*(s)+6], __uint_as_float(A3.y), d1);               \
    d1 = fmaf(wreg[1][8*(s)+7], __uint_as_float(A3.w), d1);               \
    d2 = fmaf(wreg[2][8*(s)+0], __uint_as_float(A0.y), d2);               \
    d2 = fmaf(wreg[2][8*(s)+1], __uint_as_float(A0.w), d2);               \
    d2 = fmaf(wreg[2][8*(s)+2], __uint_as_float(A1.y), d2);               \
    d2 = fmaf(wreg[2][8*(s)+3], __uint_as_float(A1.w), d2);               \
    d2 = fmaf(wreg[2][8*(s)+4], __uint_as_float(A2.y), d2);               \
    d2 = fmaf(wreg[2][8*(s)+5], __uint_as_float(A2.w), d2);               \
    d2 = fmaf(wreg[2][8*(s)+6], __uint_as_float(A3.y), d2);               \
    d2 = fmaf(wreg[2][8*(s)+7], __uint_as_float(A3.w), d2);               \
    d3 = fmaf(wreg[3][8*(s)+0], __uint_as_float(A0.y), d3);               \
    d3 = fmaf(wreg[3][8*(s)+1], __uint_as_float(A0.w), d3);               \
    d3 = fmaf(wreg[3][8*(s)+2], __uint_as_float(A1.y), d3);               \
    d3 = fmaf(wreg[3][8*(s)+3], __uint_as_float(A1.w), d3);               \
    d3 = fmaf(wreg[3][8*(s)+4], __uint_as_float(A2.y), d3);               \
    d3 = fmaf(wreg[3][8*(s)+5], __uint_as_float(A2.w), d3);               \
    d3 = fmaf(wreg[3][8*(s)+6], __uint_as_float(A3.y), d3);               \
    d3 = fmaf(wreg[3][8*(s)+7], __uint_as_float(A3.w), d3);               \
  }

__global__ __launch_bounds__(NTHR, 1) void esn_main(
    const float* __restrict__ u,
    const float* __restrict__ w_in,
    const float* __restrict__ w_res,
    const float* __restrict__ w_out,
    float* __restrict__ out,
    unsigned long long* __restrict__ pairs,
    int nrepl)
{
  const int g  = blockIdx.x;    // 0..63, one WG per CU
  const int j  = threadIdx.x;   // 0..511
  const int wv = j >> 6;        // 0..7
  const int l  = j & 63;

  // which XCD am I on? poll only that replica. Uniform per wave (SGPR).
  unsigned xcc;
  asm("s_getreg_b32 %0, hwreg(HW_REG_XCC_ID)" : "=s"(xcc));
  const unsigned ri = xcc & (unsigned)(nrepl - 1);   // nrepl is 1 or 8
  unsigned long long* __restrict__ myrep = pairs + (size_t)ri * REPL;

  __shared__ float u_s[T_STEPS];        // 32 KB (x_s staging is GONE)
  __shared__ float fresh[ROWS_PER_WG];  // this WG's newest 32 values

#pragma unroll
  for (int k = 0; k < T_STEPS / NTHR; ++k) u_s[j + NTHR * k] = u[j + NTHR * k];

  // wave wv owns rows r0..r0+3; lane l owns state cols {seg*128 + 2l, +1}
  // for all 16 segments (4 subgroups x 4 loads).
  const int r0 = g * ROWS_PER_WG + wv * ROWS_PER_WAVE;

  float wreg[ROWS_PER_WAVE][8 * NSUB];  // 128 VGPR-resident weights/thread
#pragma unroll
  for (int i = 0; i < ROWS_PER_WAVE; ++i) {
#pragma unroll
    for (int s = 0; s < NSUB; ++s) {
#pragma unroll
      for (int k = 0; k < 4; ++k) {
        const float2 a =
            *(const float2*)&w_res[(r0 + i) * HIDDEN + s * 512 + k * 128 + 2 * l];
        wreg[i][8 * s + 2 * k + 0] = a.x;
        wreg[i][8 * s + 2 * k + 1] = a.y;
      }
    }
  }
  // pin weights in VGPRs; value becomes opaque -> no refetch, no remat
#pragma unroll
  for (int i = 0; i < ROWS_PER_WAVE; ++i)
#pragma unroll
    for (int k = 0; k < 8 * NSUB; ++k)
      asm volatile("" : "+v"(wreg[i][k]));

  const float winl = w_in[r0 + (l & 3)];                             // lanes 0..3
  const float wol  = (wv == 1 && l < 32) ? w_out[g * 32 + l] : 0.f;  // wave 1

  __syncthreads();  // u_s ready

  for (int t = 0; t < T_STEPS; ++t) {
    float d0 = 0.f, d1 = 0.f, d2 = 0.f, d3 = 0.f;
    if (t > 0) {
      const unsigned want = (unsigned)(t - 1);
      const unsigned long long* base =
          myrep + (unsigned)((t - 1) & 1) * HIDDEN + 2 * l;
      POLLSUB(0)
      POLLSUB(1)
      POLLSUB(2)
      POLLSUB(3)
    }

    // reduce: DPP for intra-16 steps; permlane swaps for 16/32.
    float e0 = DPP_ADD(d0, 0xB1);   // quad_perm [1,0,3,2]  (xor 1)
    float e1 = DPP_ADD(d1, 0xB1);
    float e2 = DPP_ADD(d2, 0xB1);
    float e3 = DPP_ADD(d3, 0xB1);
    float f0 = (l & 1) ? e1 : e0;
    float f1 = (l & 1) ? e3 : e2;
    f0 = DPP_ADD(f0, 0x4E);         // quad_perm [2,3,0,1]  (xor 2)
    f1 = DPP_ADD(f1, 0x4E);
    float h = (l & 2) ? f1 : f0;
    h = DPP_ADD(h, 0x124);          // row_ror:4
    h = DPP_ADD(h, 0x128);          // row_ror:8
    PERMLANE_SUM_1632(h)

    const float ut = u_s[t];
    if (l < ROWS_PER_WAVE) {
      // fast tanh: 1 - 2/(e^{2x}+1) via v_exp_f32 (2^x) + v_rcp_f32;
      // saturates correctly; ~1e-6 abs err (R7-proven).
      const float a = fmaf(winl, ut, h);
      float z;
      asm("v_exp_f32 %0, %1" : "=v"(z) : "v"(a * 2.885390082f));
      float r;
      asm("v_rcp_f32 %0, %1" : "=v"(r) : "v"(z + 1.0f));
      fresh[wv * ROWS_PER_WAVE + l] = fmaf(-2.0f, r, 1.0f);
    }
    __syncthreads();  // the ONLY barrier: fresh[] complete

    // per-wave replica publish: wave wv stores the WG's full 32-row slice
    // to replica wv (8 parallel 256B full-line stores across the waves).
    if (wv < nrepl && l < ROWS_PER_WG) {
      const unsigned long long pk =
          ((unsigned long long)__float_as_uint(fresh[l]) << 32) | (unsigned)t;
      __hip_atomic_store(
          pairs + (size_t)wv * REPL + (t & 1) * HIDDEN + g * ROWS_PER_WG + l,
          pk, __ATOMIC_RELAXED, __HIP_MEMORY_SCOPE_AGENT);
    }
    if (wv == 1 && t >= WASHOUT) {
      // distributed readout: this WG's 32-row partial of x_t . w_out
      float part = (l < 32) ? fresh[l] * wol : 0.f;
      part = DPP_ADD(part, 0xB1);
      part = DPP_ADD(part, 0x4E);
      part = DPP_ADD(part, 0x124);
      part = DPP_ADD(part, 0x128);
      PERMLANE_SUM_1632(part)
      if (l == 0) atomicAdd(&out[t - WASHOUT], part);
    }
  }
}

extern "C" void kernel_launch(void* const* d_in, const int* in_sizes, int n_in,
                              void* d_out, int out_size, void* d_ws, size_t ws_size,
                              hipStream_t stream) {
  const float* u     = (const float*)d_in[0];
  const float* w_in  = (const float*)d_in[1];
  const float* w_res = (const float*)d_in[2];
  const float* w_out = (const float*)d_in[3];
  float* out = (float*)d_out;
  unsigned long long* pairs = (unsigned long long*)d_ws;

  // replicas need NREPL * 32 KB of ws; fall back to a single mailbox
  const int nrepl =
      (ws_size >= (size_t)NREPL * REPL * sizeof(unsigned long long)) ? NREPL : 1;

  // out accumulates atomicAdd partials -> must start at zero every call
  hipMemsetAsync(out, 0, (size_t)out_size * sizeof(float), stream);
  esn_main<<<NWG, NTHR, 0, stream>>>(u, w_in, w_res, w_out, out, pairs, nrepl);
}

// Round 10
// 19847.798 us; speedup vs baseline: 1.0332x; 1.0332x over previous
//
#include <hip/hip_runtime.h>

#define HIDDEN   2048
#define T_STEPS  8192
#define WASHOUT  200
#define NWG      64
#define NTHR     512
#define NWAVE    (NTHR / 64)                 // 8 waves
#define ROWS_PER_WG   (HIDDEN / NWG)         // 32
#define ROWS_PER_WAVE (ROWS_PER_WG / NWAVE)  // 4
#define NCHUNK   8                           // 8 chunks of 256 state elements
#define NREPL    8                           // one mailbox replica per XCD
#define REPL     (2 * HIDDEN)                // ull elements per replica (32 KB)

// ws layout: NREPL replicas of {unsigned long long pairs[2][HIDDEN]}.
// Pair = {value:hi32, step:lo32}; 0xAA poison tags self-correct across
// graph replays (stale tags never match the live want sequence).
//
// R23 (this round): OUT-OF-ORDER CONSUME-DURING-SPIN, barrier 1 deleted.
// R9 failed (+46%) because 4 sequential POLLSUBs serialized detection; R4
// failed (+6%) because 7 sequential LDS acquire spins cost more than
// barrier 1. This version keeps R7's single-detect poll (own chunk only)
// and makes intra-WG chunk exchange non-blocking: one packed u64 flag word
// per buffer (byte wv = (t-1)&0xFF, release-stored by lane 0 after the
// ds_write_b128 staging), and during every failed poll round the wave
// acquire-loads that ONE word and consumes ANY ready chunk (bitmask done,
// 8 unrolled guarded bodies, compile-time slot->register indices via
// pre-rotated weights -- R3/R16 spill lesson). A late chunk blocks nothing.
// Post-straggler exposed work drops from barrier1+128 FMA+reduce (~240ns)
// to ~flag-read+16 FMA+reduce (~155ns) for every wave.
// Reuse safety: buffer/flag parity b recurs at t+2, fenced by barrier 2 of
// t+1 (all siblings consumed step t before passing it). Flag byte
// (t-1)&0xFF != stale (t-3)&0xFF; 0xAA init can't match want=0/1.
// Kept (each isolated): per-XCD replicas (R5 win), sc1 cacheable polls /
// NO nt (R2), per-wave full-line publish + permlane swaps + fast tanh
// (R7 win), VGPR-pinned pre-rotated weights (R1/R4), launch_bounds(512,1)
// (R3/R8 reg-cap lessons), poison self-init.

// DPP add: x + dpp_perm(x). All-VALU (no DS round trip).
#define DPP_ADD(x, ctrl) ((x) + __int_as_float(__builtin_amdgcn_update_dpp( \
    0, __float_as_int(x), ctrl, 0xF, 0xF, true)))

typedef unsigned uint4v __attribute__((ext_vector_type(4)));
typedef unsigned uint2v __attribute__((ext_vector_type(2)));

// 64-lane sum via permlane{16,32}_swap self-swap (both outputs summed ->
// direction-agnostic). Builtin form only: R19's asm form let the allocator
// coalesce the two same-value "+v" operands into one register.
#define PERMLANE_SUM_1632(h)                                         \
  {                                                                  \
    uint2v s16 = __builtin_amdgcn_permlane16_swap(                   \
        __float_as_uint(h), __float_as_uint(h), false, false);       \
    h = __uint_as_float(s16.x) + __uint_as_float(s16.y);             \
    uint2v s32 = __builtin_amdgcn_permlane32_swap(                   \
        __float_as_uint(h), __float_as_uint(h), false, false);       \
    h = __uint_as_float(s32.x) + __uint_as_float(s32.y);             \
  }

// 16 FMAs of weight-slot kk (compile-time) against x4 (float4)
#define CHUNKFMA(kk, x4)                              \
  d0 = fmaf(wreg[0][4*(kk)+0], (x4).x, d0);           \
  d0 = fmaf(wreg[0][4*(kk)+1], (x4).y, d0);           \
  d0 = fmaf(wreg[0][4*(kk)+2], (x4).z, d0);           \
  d0 = fmaf(wreg[0][4*(kk)+3], (x4).w, d0);           \
  d1 = fmaf(wreg[1][4*(kk)+0], (x4).x, d1);           \
  d1 = fmaf(wreg[1][4*(kk)+1], (x4).y, d1);           \
  d1 = fmaf(wreg[1][4*(kk)+2], (x4).z, d1);           \
  d1 = fmaf(wreg[1][4*(kk)+3], (x4).w, d1);           \
  d2 = fmaf(wreg[2][4*(kk)+0], (x4).x, d2);           \
  d2 = fmaf(wreg[2][4*(kk)+1], (x4).y, d2);           \
  d2 = fmaf(wreg[2][4*(kk)+2], (x4).z, d2);           \
  d2 = fmaf(wreg[2][4*(kk)+3], (x4).w, d2);           \
  d3 = fmaf(wreg[3][4*(kk)+0], (x4).x, d3);           \
  d3 = fmaf(wreg[3][4*(kk)+1], (x4).y, d3);           \
  d3 = fmaf(wreg[3][4*(kk)+2], (x4).z, d3);           \
  d3 = fmaf(wreg[3][4*(kk)+3], (x4).w, d3);

// Try to consume weight-slot k (chunk (wv+k)&7) if flagged ready in F.
// Out-of-order: each slot guarded only by its own done-bit + flag byte.
#define TRYC(k)                                                           \
  if (!(done & (1u << (k)))) {                                            \
    const int c_ = (wv + (k)) & 7;                                        \
    if (((unsigned)(F >> (c_ * 8)) & 0xFFu) == wb) {                      \
      const float4 x4 = *(const float4*)&x_s[b][(c_ << 8) + 4 * l];       \
      CHUNKFMA(k, x4)                                                     \
      done |= 1u << (k);                                                  \
    }                                                                     \
  }

// One flag-word read, then consume every ready not-yet-consumed chunk.
#define TRYBURST                                                          \
  {                                                                       \
    const unsigned long long F = __hip_atomic_load(                       \
        &flgw[b], __ATOMIC_ACQUIRE, __HIP_MEMORY_SCOPE_WORKGROUP);        \
    TRYC(1) TRYC(2) TRYC(3) TRYC(4) TRYC(5) TRYC(6) TRYC(7)               \
  }

__global__ __launch_bounds__(NTHR, 1) void esn_main(
    const float* __restrict__ u,
    const float* __restrict__ w_in,
    const float* __restrict__ w_res,
    const float* __restrict__ w_out,
    float* __restrict__ out,
    unsigned long long* __restrict__ pairs,
    int nrepl)
{
  const int g  = blockIdx.x;    // 0..63, one WG per CU
  const int j  = threadIdx.x;   // 0..511
  const int wv = j >> 6;        // 0..7
  const int l  = j & 63;

  // which XCD am I on? poll only that replica. Uniform per wave (SGPR).
  unsigned xcc;
  asm("s_getreg_b32 %0, hwreg(HW_REG_XCC_ID)" : "=s"(xcc));
  const unsigned ri = xcc & (unsigned)(nrepl - 1);   // nrepl is 1 or 8
  unsigned long long* __restrict__ myrep = pairs + (size_t)ri * REPL;

  __shared__ float x_s[2][HIDDEN];         // double-buffered staged state
  __shared__ float u_s[T_STEPS];           // 32 KB
  __shared__ float fresh[ROWS_PER_WG];     // this WG's newest 32 values
  __shared__ unsigned long long flgw[2];   // packed per-chunk flag bytes

  if (j < 2) flgw[j] = 0xAAAAAAAAAAAAAAAAull;  // poison != any (t-1)&0xFF early

#pragma unroll
  for (int k = 0; k < T_STEPS / NTHR; ++k) u_s[j + NTHR * k] = u[j + NTHR * k];

  // wave wv owns rows r0..r0+3; weight slot k holds chunk (wv+k)&7 so all
  // consume-time register indices are compile-time (pre-rotated layout).
  const int r0 = g * ROWS_PER_WG + wv * ROWS_PER_WAVE;

  float wreg[ROWS_PER_WAVE][4 * NCHUNK];  // 128 register-resident weights
#pragma unroll
  for (int i = 0; i < ROWS_PER_WAVE; ++i) {
#pragma unroll
    for (int k = 0; k < NCHUNK; ++k) {
      const int c = (wv + k) & 7;
      const float4 a = *(const float4*)&w_res[(r0 + i) * HIDDEN + c * 256 + 4 * l];
      wreg[i][4 * k + 0] = a.x; wreg[i][4 * k + 1] = a.y;
      wreg[i][4 * k + 2] = a.z; wreg[i][4 * k + 3] = a.w;
    }
  }
  // pin weights; value becomes opaque -> no refetch, no remat in t-loop
#pragma unroll
  for (int i = 0; i < ROWS_PER_WAVE; ++i)
#pragma unroll
    for (int k = 0; k < 4 * NCHUNK; ++k)
      asm volatile("" : "+v"(wreg[i][k]));

  const float winl = w_in[r0 + (l & 3)];                             // lanes 0..3
  const float wol  = (wv == 1 && l < 32) ? w_out[g * 32 + l] : 0.f;  // wave 1

  __syncthreads();  // u_s + flgw ready

  for (int t = 0; t < T_STEPS; ++t) {
    float d0 = 0.f, d1 = 0.f, d2 = 0.f, d3 = 0.f;
    const unsigned b = (unsigned)((t - 1) & 1);
    if (t > 0) {
      const unsigned want = (unsigned)(t - 1);
      const unsigned wb   = want & 0xFFu;
      unsigned done = 0;
      // wave wv polls only its own chunk of ITS XCD'S REPLICA (2x16B sc1,
      // L2-served spin); between failed rounds it consumes any sibling
      // chunk already staged (TRYBURST: 1 flag word + out-of-order FMAs).
      const unsigned long long* bp = myrep + b * HIDDEN + (wv << 8) + 4 * l;
      uint4v A, B;   // [tag0, val0, tag1, val1]
      for (;;) {
        asm volatile(
            "global_load_dwordx4 %0, %2, off sc1\n\t"
            "global_load_dwordx4 %1, %3, off sc1\n\t"
            "s_waitcnt vmcnt(0)"
            : "=&v"(A), "=&v"(B)
            : "v"(bp), "v"(bp + 2)
            : "memory");
        if (((A.x == want) & (A.z == want)) &
            ((B.x == want) & (B.z == want))) break;
        TRYBURST
      }
      float4 xv;
      xv.x = __uint_as_float(A.y);
      xv.y = __uint_as_float(A.w);
      xv.z = __uint_as_float(B.y);
      xv.w = __uint_as_float(B.w);
      // stage + flag FIRST (unblocks siblings), then own-chunk FMAs
      *(float4*)&x_s[b][(wv << 8) + 4 * l] = xv;  // one ds_write_b128
      if (l == 0)  // wave-level lgkmcnt drain orders all 64 lanes' writes
        __hip_atomic_store((unsigned char*)&flgw[b] + wv, (unsigned char)wb,
                           __ATOMIC_RELEASE, __HIP_MEMORY_SCOPE_WORKGROUP);
      CHUNKFMA(0, xv)   // own chunk straight from poll registers
      while (done != 0xFEu) { TRYBURST }   // drain remaining slots 1..7
    }

    // reduce: DPP for intra-16 steps; permlane swaps for 16/32.
    float e0 = DPP_ADD(d0, 0xB1);   // quad_perm [1,0,3,2]  (xor 1)
    float e1 = DPP_ADD(d1, 0xB1);
    float e2 = DPP_ADD(d2, 0xB1);
    float e3 = DPP_ADD(d3, 0xB1);
    float f0 = (l & 1) ? e1 : e0;
    float f1 = (l & 1) ? e3 : e2;
    f0 = DPP_ADD(f0, 0x4E);         // quad_perm [2,3,0,1]  (xor 2)
    f1 = DPP_ADD(f1, 0x4E);
    float h = (l & 2) ? f1 : f0;
    h = DPP_ADD(h, 0x124);          // row_ror:4
    h = DPP_ADD(h, 0x128);          // row_ror:8
    PERMLANE_SUM_1632(h)

    const float ut = u_s[t];
    if (l < ROWS_PER_WAVE) {
      // fast tanh: 1 - 2/(e^{2x}+1) via v_exp_f32 (2^x) + v_rcp_f32;
      // saturates correctly; ~1e-6 abs err (R7-proven).
      const float a = fmaf(winl, ut, h);
      float z;
      asm("v_exp_f32 %0, %1" : "=v"(z) : "v"(a * 2.885390082f));
      float r;
      asm("v_rcp_f32 %0, %1" : "=v"(r) : "v"(z + 1.0f));
      fresh[wv * ROWS_PER_WAVE + l] = fmaf(-2.0f, r, 1.0f);
    }
    __syncthreads();  // the ONLY barrier: fresh[] complete; also fences
                      // x_s/flgw parity reuse (b recurs after 2 barriers)

    // per-wave replica publish: wave wv stores the WG's full 32-row slice
    // to replica wv (8 parallel 256B full-line stores across the waves).
    if (wv < nrepl && l < ROWS_PER_WG) {
      const unsigned long long pk =
          ((unsigned long long)__float_as_uint(fresh[l]) << 32) | (unsigned)t;
      __hip_atomic_store(
          pairs + (size_t)wv * REPL + (t & 1) * HIDDEN + g * ROWS_PER_WG + l,
          pk, __ATOMIC_RELAXED, __HIP_MEMORY_SCOPE_AGENT);
    }
    if (wv == 1 && t >= WASHOUT) {
      // distributed readout: this WG's 32-row partial of x_t . w_out
      float part = (l < 32) ? fresh[l] * wol : 0.f;
      part = DPP_ADD(part, 0xB1);
      part = DPP_ADD(part, 0x4E);
      part = DPP_ADD(part, 0x124);
      part = DPP_ADD(part, 0x128);
      PERMLANE_SUM_1632(part)
      if (l == 0) atomicAdd(&out[t - WASHOUT], part);
    }
  }
}

extern "C" void kernel_launch(void* const* d_in, const int* in_sizes, int n_in,
                              void* d_out, int out_size, void* d_ws, size_t ws_size,
                              hipStream_t stream) {
  const float* u     = (const float*)d_in[0];
  const float* w_in  = (const float*)d_in[1];
  const float* w_res = (const float*)d_in[2];
  const float* w_out = (const float*)d_in[3];
  float* out = (float*)d_out;
  unsigned long long* pairs = (unsigned long long*)d_ws;

  // replicas need NREPL * 32 KB of ws; fall back to a single mailbox
  const int nrepl =
      (ws_size >= (size_t)NREPL * REPL * sizeof(unsigned long long)) ? NREPL : 1;

  // out accumulates atomicAdd partials -> must start at zero every call
  hipMemsetAsync(out, 0, (size_t)out_size * sizeof(float), stream);
  esn_main<<<NWG, NTHR, 0, stream>>>(u, w_in, w_res, w_out, out, pairs, nrepl);
}

// Round 11
// 14603.096 us; speedup vs baseline: 1.4043x; 1.3592x over previous
//
#include <hip/hip_runtime.h>

#define HIDDEN   2048
#define T_STEPS  8192
#define WASHOUT  200
#define NWG      64
#define NTHR     1024
#define NWAVE    (NTHR / 64)                 // 16 waves
#define ROWS_PER_WG   (HIDDEN / NWG)         // 32
#define ROWS_PER_WAVE (ROWS_PER_WG / NWAVE)  // 2
#define NCHUNK   16                          // 16 chunks of 128 state elements
#define NREPL    8                           // one mailbox replica per XCD
#define REPL     (2 * HIDDEN)                // ull elements per replica (32 KB)

// ws layout: NREPL replicas of {unsigned long long pairs[2][HIDDEN]}.
// Pair = {value:hi32, step:lo32}; 0xAA poison tags self-correct across
// graph replays (stale tags never match the live want sequence).
//
// R24 (this round): re-land R8's 16-wave config with the AGPR disease
// fixed. R8's tell: VGPR_Count=48 < 64 pinned weights -- the one-time
// "+v" pin only forces VGPR residency at that point; under the 128-reg
// cap of a 1024-thr block, regalloc then STORED the weights in AGPRs and
// paid an accvgpr_read per FMA (R0's disease), erasing the FMA halving.
// Fix: re-pin every weight INSIDE the t-loop (zero-instruction asm at
// loop top). AGPR storage now costs 64 copies/iter vs 64 VGPRs of
// pressure (64+~30 < 128 cap) -> regalloc must keep them VGPR-resident.
// Diagnostic in counters: VGPR_Count >= ~90 = landed; ~48 = failed.
// R10 post-mortem: consume-during-spin (3rd attempt at removing barrier
// 1) regressed again -- spin rounds bloated 3-4x, detection delayed.
// Two-barrier skeleton is final.
// Budget recalibrated from R2's nt datapoint: wire ~0.55us/step, compute
// ~1.1us -> compute thinning (this round) is the right lever.
// Kept (each isolated): per-XCD replicas (R5), sc1 cacheable polls / NO
// nt (R2), per-wave full-line publish + permlane swaps + fast tanh (R7),
// two barriers (R4/R9/R10), poison self-init.

// DPP add: x + dpp_perm(x). All-VALU (no DS round trip).
#define DPP_ADD(x, ctrl) ((x) + __int_as_float(__builtin_amdgcn_update_dpp( \
    0, __float_as_int(x), ctrl, 0xF, 0xF, true)))

typedef unsigned uint4v __attribute__((ext_vector_type(4)));
typedef unsigned uint2v __attribute__((ext_vector_type(2)));

// 64-lane sum via permlane{16,32}_swap self-swap (both outputs summed ->
// direction-agnostic). Builtin form only: R19's asm form let the allocator
// coalesce the two same-value "+v" operands into one register.
#define PERMLANE_SUM_1632(h)                                         \
  {                                                                  \
    uint2v s16 = __builtin_amdgcn_permlane16_swap(                   \
        __float_as_uint(h), __float_as_uint(h), false, false);       \
    h = __uint_as_float(s16.x) + __uint_as_float(s16.y);             \
    uint2v s32 = __builtin_amdgcn_permlane32_swap(                   \
        __float_as_uint(h), __float_as_uint(h), false, false);       \
    h = __uint_as_float(s32.x) + __uint_as_float(s32.y);             \
  }

__global__ __launch_bounds__(NTHR, 1) void esn_main(
    const float* __restrict__ u,
    const float* __restrict__ w_in,
    const float* __restrict__ w_res,
    const float* __restrict__ w_out,
    float* __restrict__ out,
    unsigned long long* __restrict__ pairs,
    int nrepl)
{
  const int g  = blockIdx.x;    // 0..63, one WG per CU
  const int j  = threadIdx.x;   // 0..1023
  const int wv = j >> 6;        // 0..15
  const int l  = j & 63;

  // which XCD am I on? poll only that replica. Uniform per wave (SGPR).
  unsigned xcc;
  asm("s_getreg_b32 %0, hwreg(HW_REG_XCC_ID)" : "=s"(xcc));
  const unsigned ri = xcc & (unsigned)(nrepl - 1);   // nrepl is 1 or 8
  unsigned long long* __restrict__ myrep = pairs + (size_t)ri * REPL;

  __shared__ float x_s[2][HIDDEN];      // double-buffered staged state (16 KB)
  __shared__ float u_s[T_STEPS];        // 32 KB
  __shared__ float fresh[ROWS_PER_WG];  // this WG's newest 32 values

#pragma unroll
  for (int k = 0; k < T_STEPS / NTHR; ++k) u_s[j + NTHR * k] = u[j + NTHR * k];

  // wave wv owns rows r0..r0+1 and state chunk wv (elements wv*128..+127);
  // lane l owns cols {c*128 + 2l, +1} of each chunk c.
  const int r0 = g * ROWS_PER_WG + wv * ROWS_PER_WAVE;

  float wreg[ROWS_PER_WAVE][2 * NCHUNK];  // 64 VGPR-resident weights/thread
#pragma unroll
  for (int i = 0; i < ROWS_PER_WAVE; ++i) {
#pragma unroll
    for (int c = 0; c < NCHUNK; ++c) {
      const float2 a = *(const float2*)&w_res[(r0 + i) * HIDDEN + c * 128 + 2 * l];
      wreg[i][2 * c + 0] = a.x; wreg[i][2 * c + 1] = a.y;
    }
  }

  const float winl = w_in[r0 + (l & 1)];                             // lanes 0..1
  const float wol  = (wv == 8 && l < 32) ? w_out[g * 32 + l] : 0.f;  // wave 8

  __syncthreads();  // u_s ready

  for (int t = 0; t < T_STEPS; ++t) {
    // RE-PIN the weights every iteration (zero-instruction asm): makes
    // AGPR storage cost 64 copies/iter in regalloc's model, forcing
    // VGPR residency under the 1024-thr 128-reg cap (R8's failure mode).
#pragma unroll
    for (int i = 0; i < ROWS_PER_WAVE; ++i)
#pragma unroll
      for (int k = 0; k < 2 * NCHUNK; ++k)
        asm volatile("" : "+v"(wreg[i][k]));

    float d0 = 0.f, d1 = 0.f;
    const unsigned b = (unsigned)((t - 1) & 1);
    if (t > 0) {
      const unsigned want = (unsigned)(t - 1);
      // wave wv polls its 128-pair chunk of ITS XCD'S REPLICA:
      // ONE 16B sc1 load per lane per round (2 pairs).
      const unsigned long long* bp = myrep + b * HIDDEN + (wv << 7) + 2 * l;
      uint4v A;   // [tag0, val0, tag1, val1]
      for (;;) {
        asm volatile(
            "global_load_dwordx4 %0, %1, off sc1\n\t"
            "s_waitcnt vmcnt(0)"
            : "=&v"(A)
            : "v"(bp)
            : "memory");
        if ((A.x == want) & (A.z == want)) break;
      }
      float2 xv;
      xv.x = __uint_as_float(A.y);
      xv.y = __uint_as_float(A.w);
      *(float2*)&x_s[b][(wv << 7) + 2 * l] = xv;  // one ds_write_b64
    }
    __syncthreads();  // barrier 1: all chunks staged

    if (t > 0) {
#pragma unroll
      for (int c = 0; c < NCHUNK; ++c) {
        const float2 x2 = *(const float2*)&x_s[b][(c << 7) + 2 * l];
        d0 = fmaf(wreg[0][2 * c + 0], x2.x, d0);
        d0 = fmaf(wreg[0][2 * c + 1], x2.y, d0);
        d1 = fmaf(wreg[1][2 * c + 0], x2.x, d1);
        d1 = fmaf(wreg[1][2 * c + 1], x2.y, d1);
      }
    }

    // reduce: parity-preserving all-VALU chain. After xor1+select, even
    // lanes carry row0 partials, odd lanes row1; xor2/ror4/ror8/swap16/
    // swap32 all preserve lane parity -> lane 0 = row r0, lane 1 = r0+1.
    float e0 = DPP_ADD(d0, 0xB1);   // quad_perm [1,0,3,2]  (xor 1)
    float e1 = DPP_ADD(d1, 0xB1);
    float h = (l & 1) ? e1 : e0;
    h = DPP_ADD(h, 0x4E);           // quad_perm [2,3,0,1]  (xor 2)
    h = DPP_ADD(h, 0x124);          // row_ror:4
    h = DPP_ADD(h, 0x128);          // row_ror:8
    PERMLANE_SUM_1632(h)

    const float ut = u_s[t];
    if (l < ROWS_PER_WAVE) {
      // fast tanh: 1 - 2/(e^{2x}+1) via v_exp_f32 (2^x) + v_rcp_f32;
      // saturates correctly; ~1e-6 abs err (R7-proven).
      const float a = fmaf(winl, ut, h);
      float z;
      asm("v_exp_f32 %0, %1" : "=v"(z) : "v"(a * 2.885390082f));
      float r;
      asm("v_rcp_f32 %0, %1" : "=v"(r) : "v"(z + 1.0f));
      fresh[wv * ROWS_PER_WAVE + l] = fmaf(-2.0f, r, 1.0f);
    }
    __syncthreads();  // barrier 2: fresh[] complete

    // per-wave replica publish: wave wv (0..7) stores the WG's full 32-row
    // slice to replica wv (8 parallel 256B full-line stores).
    if (wv < nrepl && l < ROWS_PER_WG) {
      const unsigned long long pk =
          ((unsigned long long)__float_as_uint(fresh[l]) << 32) | (unsigned)t;
      __hip_atomic_store(
          pairs + (size_t)wv * REPL + (t & 1) * HIDDEN + g * ROWS_PER_WG + l,
          pk, __ATOMIC_RELAXED, __HIP_MEMORY_SCOPE_AGENT);
    }
    if (wv == 8 && t >= WASHOUT) {
      // distributed readout on a NON-publishing wave: this WG's 32-row
      // partial of x_t . w_out, all-VALU reduce (lanes >=32 contribute 0).
      float part = (l < 32) ? fresh[l] * wol : 0.f;
      part = DPP_ADD(part, 0xB1);
      part = DPP_ADD(part, 0x4E);
      part = DPP_ADD(part, 0x124);
      part = DPP_ADD(part, 0x128);
      PERMLANE_SUM_1632(part)
      if (l == 0) atomicAdd(&out[t - WASHOUT], part);
    }
  }
}

extern "C" void kernel_launch(void* const* d_in, const int* in_sizes, int n_in,
                              void* d_out, int out_size, void* d_ws, size_t ws_size,
                              hipStream_t stream) {
  const float* u     = (const float*)d_in[0];
  const float* w_in  = (const float*)d_in[1];
  const float* w_res = (const float*)d_in[2];
  const float* w_out = (const float*)d_in[3];
  float* out = (float*)d_out;
  unsigned long long* pairs = (unsigned long long*)d_ws;

  // replicas need NREPL * 32 KB of ws; fall back to a single mailbox
  const int nrepl =
      (ws_size >= (size_t)NREPL * REPL * sizeof(unsigned long long)) ? NREPL : 1;

  // out accumulates atomicAdd partials -> must start at zero every call
  hipMemsetAsync(out, 0, (size_t)out_size * sizeof(float), stream);
  esn_main<<<NWG, NTHR, 0, stream>>>(u, w_in, w_res, w_out, out, pairs, nrepl);
}

// Round 12
// 14045.857 us; speedup vs baseline: 1.4600x; 1.0397x over previous
//
#include <hip/hip_runtime.h>

#define HIDDEN   2048
#define T_STEPS  8192
#define WASHOUT  200
#define NWG      64
#define NTHR     512
#define NWAVE    (NTHR / 64)                 // 8 waves
#define ROWS_PER_WG   (HIDDEN / NWG)         // 32
#define ROWS_PER_WAVE (ROWS_PER_WG / NWAVE)  // 4
#define NCHUNK   8                           // 8 chunks of 256 state elements
#define NREPL    8                           // one mailbox replica per XCD
#define REPL     (2 * HIDDEN)                // ull elements per replica (32 KB)

// ws layout: NREPL replicas of {unsigned long long pairs[2][HIDDEN]}.
// Pair = {value:hi32, step:lo32}: one 8B unit carries payload+tag.
// 0xAA poison tags self-correct across graph replays.
//
// R25 (final structure): exact revert to the R7/R20 winner (14.06 ms,
// 1.72 us/step) per the R10 pre-commitment. R11's in-loop re-pin failed
// (VGPR_Count=48 again): at 1024 thr the 128-reg cap makes regalloc park
// the weights in AGPRs regardless of source-level pins -> 16-wave configs
// are structurally dead, like single-XCD (R3, register arithmetic).
//
// Falsified this session: scatter publish (R1), nt polls (R2, 1.6x),
// single-XCD (R3), in-order LDS flags (R4), nt publish (R4), serial
// subgroup poll (R9, 1.46x), OoO consume-during-spin (R10, 1.41x),
// 16-wave (R8/R11, AGPR disease). Confirmed: per-XCD replicas (R5, -8%),
// tail shave permlane+fast-tanh+per-wave-publish (R7, -13.5%).
// Remaining budget: ~0.55-1.0 us/step cross-XCD store->invalidate->
// refetch wire (attacked from every side; protocol floor) + ~0.6 us
// compute/stage/barriers that resists thinning at this register budget.

// DPP add: x + dpp_perm(x). All-VALU (no DS round trip).
#define DPP_ADD(x, ctrl) ((x) + __int_as_float(__builtin_amdgcn_update_dpp( \
    0, __float_as_int(x), ctrl, 0xF, 0xF, true)))

typedef unsigned uint4v __attribute__((ext_vector_type(4)));
typedef unsigned uint2v __attribute__((ext_vector_type(2)));

__global__ __launch_bounds__(NTHR, 1) void esn_main(
    const float* __restrict__ u,
    const float* __restrict__ w_in,
    const float* __restrict__ w_res,
    const float* __restrict__ w_out,
    float* __restrict__ out,
    unsigned long long* __restrict__ pairs,
    int nrepl)
{
  const int g  = blockIdx.x;    // 0..63, one WG per CU
  const int j  = threadIdx.x;   // 0..511
  const int wv = j >> 6;        // 0..7
  const int l  = j & 63;

  // which XCD am I on? poll only that replica. Uniform per wave (SGPR).
  unsigned xcc;
  asm("s_getreg_b32 %0, hwreg(HW_REG_XCC_ID)" : "=s"(xcc));
  const unsigned ri = xcc & (unsigned)(nrepl - 1);   // nrepl is 1 or 8
  unsigned long long* __restrict__ myrep = pairs + (size_t)ri * REPL;

  __shared__ float x_s[2][HIDDEN];      // double-buffered staged state (16 KB)
  __shared__ float u_s[T_STEPS];        // 32 KB
  __shared__ float fresh[ROWS_PER_WG];  // this WG's newest 32 values

#pragma unroll
  for (int k = 0; k < T_STEPS / NTHR; ++k) u_s[j + NTHR * k] = u[j + NTHR * k];

  // wave wv owns rows r0..r0+3; lane l owns cols {c*256 + 4l .. +3}
  const int r0 = g * ROWS_PER_WG + wv * ROWS_PER_WAVE;

  float wreg[ROWS_PER_WAVE][4 * NCHUNK];  // 128 VGPR-resident weights/thread
#pragma unroll
  for (int i = 0; i < ROWS_PER_WAVE; ++i) {
#pragma unroll
    for (int c = 0; c < NCHUNK; ++c) {
      const float4 a = *(const float4*)&w_res[(r0 + i) * HIDDEN + c * 256 + 4 * l];
      wreg[i][4 * c + 0] = a.x; wreg[i][4 * c + 1] = a.y;
      wreg[i][4 * c + 2] = a.z; wreg[i][4 * c + 3] = a.w;
    }
  }
  // pin weights in VGPRs; value becomes opaque -> no refetch, no remat
#pragma unroll
  for (int i = 0; i < ROWS_PER_WAVE; ++i)
#pragma unroll
    for (int k = 0; k < 4 * NCHUNK; ++k)
      asm volatile("" : "+v"(wreg[i][k]));

  const float winl = w_in[r0 + (l & 3)];                             // lanes 0..3
  const float wol  = (wv == 1 && l < 32) ? w_out[g * 32 + l] : 0.f;  // wave 1

  __syncthreads();  // u_s ready

  for (int t = 0; t < T_STEPS; ++t) {
    float d0 = 0.f, d1 = 0.f, d2 = 0.f, d3 = 0.f;
    const unsigned b = (unsigned)((t - 1) & 1);
    if (t > 0) {
      const unsigned want = (unsigned)(t - 1);
      // wave wv polls only its own chunk OF ITS XCD'S REPLICA;
      // 2x16B sc1 loads -> spin served from the local L2.
      const unsigned long long* bp = myrep + b * HIDDEN + (wv << 8) + 4 * l;
      uint4v A, B;   // [tag0, val0, tag1, val1]
      for (;;) {
        asm volatile(
            "global_load_dwordx4 %0, %2, off sc1\n\t"
            "global_load_dwordx4 %1, %3, off sc1\n\t"
            "s_waitcnt vmcnt(0)"
            : "=&v"(A), "=&v"(B)
            : "v"(bp), "v"(bp + 2)
            : "memory");
        if (((A.x == want) & (A.z == want)) &
            ((B.x == want) & (B.z == want))) break;
      }
      float4 xv;
      xv.x = __uint_as_float(A.y);
      xv.y = __uint_as_float(A.w);
      xv.z = __uint_as_float(B.y);
      xv.w = __uint_as_float(B.w);
      *(float4*)&x_s[b][(wv << 8) + 4 * l] = xv;  // one ds_write_b128
    }
    __syncthreads();  // barrier 1: all chunks staged

    if (t > 0) {
      const float4* xs4 = (const float4*)x_s[b];
#define ROWFMA(i, di)                            \
      di = fmaf(wreg[i][4*c+0], x4.x, di);       \
      di = fmaf(wreg[i][4*c+1], x4.y, di);       \
      di = fmaf(wreg[i][4*c+2], x4.z, di);       \
      di = fmaf(wreg[i][4*c+3], x4.w, di);
#pragma unroll
      for (int c = 0; c < NCHUNK; ++c) {
        const float4 x4 = xs4[(c << 6) + l];   // ds_read_b128
        ROWFMA(0, d0)
        ROWFMA(1, d1)
        ROWFMA(2, d2)
        ROWFMA(3, d3)
      }
#undef ROWFMA
    }

    // reduce: DPP for intra-16 steps; permlane swaps (pure VALU, no LDS
    // round trip) for the 16/32 cross-group steps.
    float e0 = DPP_ADD(d0, 0xB1);   // quad_perm [1,0,3,2]  (xor 1)
    float e1 = DPP_ADD(d1, 0xB1);
    float e2 = DPP_ADD(d2, 0xB1);
    float e3 = DPP_ADD(d3, 0xB1);
    float f0 = (l & 1) ? e1 : e0;
    float f1 = (l & 1) ? e3 : e2;
    f0 = DPP_ADD(f0, 0x4E);         // quad_perm [2,3,0,1]  (xor 2)
    f1 = DPP_ADD(f1, 0x4E);
    float h = (l & 2) ? f1 : f0;
    h = DPP_ADD(h, 0x124);          // row_ror:4
    h = DPP_ADD(h, 0x128);          // row_ror:8
#if __has_builtin(__builtin_amdgcn_permlane16_swap) && \
    __has_builtin(__builtin_amdgcn_permlane32_swap)
    {
      // h += h^16 then h += h^32. Builtin returns BOTH outputs (uint2) ->
      // distinct registers guaranteed (R19's asm self-swap coalesced the
      // two "+v" operands into one reg and corrupted the sums).
      uint2v s16 = __builtin_amdgcn_permlane16_swap(
          __float_as_uint(h), __float_as_uint(h), false, false);
      h = __uint_as_float(s16.x) + __uint_as_float(s16.y);
      uint2v s32 = __builtin_amdgcn_permlane32_swap(
          __float_as_uint(h), __float_as_uint(h), false, false);
      h = __uint_as_float(s32.x) + __uint_as_float(s32.y);
    }
#else
    h += __shfl_xor(h, 16, 64);
    h += __shfl_xor(h, 32, 64);
#endif

    const float ut = u_s[t];
    if (l < ROWS_PER_WAVE) {
      // fast tanh: 1 - 2/(e^{2x}+1) via v_exp_f32 (2^x) + v_rcp_f32;
      // saturates correctly via exp overflow/underflow; ~1e-6 abs err.
      const float a = fmaf(winl, ut, h);
      float z;
      asm("v_exp_f32 %0, %1" : "=v"(z) : "v"(a * 2.885390082f));
      float r;
      asm("v_rcp_f32 %0, %1" : "=v"(r) : "v"(z + 1.0f));
      fresh[wv * ROWS_PER_WAVE + l] = fmaf(-2.0f, r, 1.0f);
    }
    __syncthreads();  // barrier 2: fresh[] complete

    // per-wave replica publish: wave wv stores the WG's full 32-row slice
    // to replica wv (8 parallel 256B full-line stores across the waves).
    if (wv < nrepl && l < ROWS_PER_WG) {
      const unsigned long long pk =
          ((unsigned long long)__float_as_uint(fresh[l]) << 32) | (unsigned)t;
      __hip_atomic_store(
          pairs + (size_t)wv * REPL + (t & 1) * HIDDEN + g * ROWS_PER_WG + l,
          pk, __ATOMIC_RELAXED, __HIP_MEMORY_SCOPE_AGENT);
    }
    if (wv == 1 && t >= WASHOUT) {
      // distributed readout: this WG's 32-row partial of x_t . w_out
      float part = (l < 32) ? fresh[l] * wol : 0.f;
      part += __shfl_xor(part, 32, 64);
      part += __shfl_xor(part, 16, 64);
      part += __shfl_xor(part, 8, 64);
      part += __shfl_xor(part, 4, 64);
      part += __shfl_xor(part, 2, 64);
      part += __shfl_xor(part, 1, 64);
      if (l == 0) atomicAdd(&out[t - WASHOUT], part);
    }
  }
}

extern "C" void kernel_launch(void* const* d_in, const int* in_sizes, int n_in,
                              void* d_out, int out_size, void* d_ws, size_t ws_size,
                              hipStream_t stream) {
  const float* u     = (const float*)d_in[0];
  const float* w_in  = (const float*)d_in[1];
  const float* w_res = (const float*)d_in[2];
  const float* w_out = (const float*)d_in[3];
  float* out = (float*)d_out;
  unsigned long long* pairs = (unsigned long long*)d_ws;

  // replicas need NREPL * 32 KB of ws; fall back to a single mailbox
  const int nrepl =
      (ws_size >= (size_t)NREPL * REPL * sizeof(unsigned long long)) ? NREPL : 1;

  // out accumulates atomicAdd partials -> must start at zero every call
  hipMemsetAsync(out, 0, (size_t)out_size * sizeof(float), stream);
  esn_main<<<NWG, NTHR, 0, stream>>>(u, w_in, w_res, w_out, out, pairs, nrepl);
}